// Round 13
// baseline (609.349 us; speedup 1.0000x reference)
//
#include <hip/hip_runtime.h>
#include <math.h>

#define T_TOK 8192
#define DDIM 1024
#define HDIM 2048
#define NE 8

typedef float f32x4 __attribute__((ext_vector_type(4)));
typedef short short8 __attribute__((ext_vector_type(8)));
typedef __attribute__((address_space(3))) char as3_char;
typedef __attribute__((address_space(1))) const char as1_cchar;

__device__ __forceinline__ unsigned f2bf(float f) {
  unsigned u = __float_as_uint(f);
  return (u + 0x7fffu + ((u >> 16) & 1u)) >> 16;
}
__device__ __forceinline__ float gelu_exact(float v) {
  return 0.5f * v * (1.0f + erff(v * 0.70710678118654752f));
}

// ---------------- transpose + cast: in [E][R][C] f32 -> out [E][C][R] bf16, 64x64 tiles ----
__device__ __forceinline__ void transpose_body(const float* __restrict__ in,
                                               unsigned short* __restrict__ out,
                                               int R, int C, int e, int bx, int by,
                                               float (*tile)[65]) {
  size_t eoff = (size_t)e * R * C;
  const int r0 = by << 6, c0 = bx << 6;
  const int tid = threadIdx.x;
  const int lr = tid >> 4;          // 0..15
  const int lc4 = (tid & 15) << 2;  // 0,4,..,60
#pragma unroll
  for (int rr = 0; rr < 4; ++rr) {
    int r = lr + rr * 16;
    float4 v = *(const float4*)(in + eoff + (size_t)(r0 + r) * C + c0 + lc4);
    tile[r][lc4] = v.x; tile[r][lc4 + 1] = v.y; tile[r][lc4 + 2] = v.z; tile[r][lc4 + 3] = v.w;
  }
  __syncthreads();
  const int c = tid >> 2;           // 0..63
  const int rch = (tid & 3) << 4;   // 0,16,32,48
  unsigned short tmp[16];
#pragma unroll
  for (int i = 0; i < 16; ++i) tmp[i] = (unsigned short)f2bf(tile[rch + i][c]);
  unsigned short* dst = out + eoff + (size_t)(c0 + c) * R + r0 + rch;
  *(uint4*)dst = *(const uint4*)tmp;
  *(uint4*)(dst + 8) = *(const uint4*)(tmp + 8);
}

// standalone transpose kernel (fallback path: Wd after up_gemm frees the region)
__global__ __launch_bounds__(256) void transpose_cast64(const float* __restrict__ in,
                                                        unsigned short* __restrict__ out,
                                                        int R, int C) {
  __shared__ float tile[64][65];
  transpose_body(in, out, R, C, blockIdx.z, blockIdx.x, blockIdx.y, tile);
}

// ---------------- fused prep: cast_x | Wu-transpose | router | zero-out | [Wd-transpose] ----
__global__ __launch_bounds__(256) void prep_kernel(
    const float* __restrict__ x, const float* __restrict__ noise,
    const float* __restrict__ Wg, const float* __restrict__ bg,
    const float* __restrict__ Wn, const float* __restrict__ bn,
    const float* __restrict__ Wu, const float* __restrict__ Wd,
    unsigned short* __restrict__ xb, unsigned short* __restrict__ WuT,
    unsigned short* __restrict__ WdT,
    int* __restrict__ e0e1, float2* __restrict__ gg, float4* __restrict__ out4) {
  __shared__ float tile[64][65];
  const int id = blockIdx.x;
  const int tid = threadIdx.x;

  if (id < 4096) {
    // ---- cast x -> bf16 ----
    const int i = id * 256 + tid;
    const float4* x4 = (const float4*)x;
    float4 a = x4[2 * i], b = x4[2 * i + 1];
    uint4 o;
    o.x = f2bf(a.x) | (f2bf(a.y) << 16);
    o.y = f2bf(a.z) | (f2bf(a.w) << 16);
    o.z = f2bf(b.x) | (f2bf(b.y) << 16);
    o.w = f2bf(b.z) | (f2bf(b.w) << 16);
    ((uint4*)xb)[i] = o;
  } else if (id < 8192) {
    // ---- Wu [E][D][H] -> WuT [E][H][D] bf16 ----
    const int t = id - 4096;
    const int e = t >> 9, rem = t & 511;
    transpose_body(Wu, WuT, DDIM, HDIM, e, rem & 31, rem >> 5, tile);
  } else if (id < 10240) {
    // ---- router: 4 tokens/block, wave per token, fp64 dots on NATURAL Wg/Wn ----
    const int wid = tid >> 6, l = tid & 63;
    const int t = (id - 8192) * 4 + wid;
    double lg[8] = {0, 0, 0, 0, 0, 0, 0, 0}, ln[8] = {0, 0, 0, 0, 0, 0, 0, 0};
    const float* xp = x + (size_t)t * DDIM;
#pragma unroll
    for (int i = 0; i < 16; ++i) {
      int d = i * 64 + l;
      float xv = xp[d];
      const float4* w4 = (const float4*)(Wg + d * 8);
      float4 wa = w4[0], wb = w4[1];
      lg[0] += (double)xv * wa.x; lg[1] += (double)xv * wa.y;
      lg[2] += (double)xv * wa.z; lg[3] += (double)xv * wa.w;
      lg[4] += (double)xv * wb.x; lg[5] += (double)xv * wb.y;
      lg[6] += (double)xv * wb.z; lg[7] += (double)xv * wb.w;
      const float4* n4 = (const float4*)(Wn + d * 8);
      float4 na = n4[0], nb = n4[1];
      ln[0] += (double)xv * na.x; ln[1] += (double)xv * na.y;
      ln[2] += (double)xv * na.z; ln[3] += (double)xv * na.w;
      ln[4] += (double)xv * nb.x; ln[5] += (double)xv * nb.y;
      ln[6] += (double)xv * nb.z; ln[7] += (double)xv * nb.w;
    }
#pragma unroll
    for (int e = 0; e < 8; ++e) {
#pragma unroll
      for (int off = 1; off < 64; off <<= 1) {
        lg[e] += __shfl_xor(lg[e], off);
        ln[e] += __shfl_xor(ln[e], off);
      }
    }
    double nv[8];
#pragma unroll
    for (int e = 0; e < 8; ++e) {
      double nl = ln[e] + (double)bn[e];
      double sp = (nl > 30.0) ? nl : log1p(exp(nl));
      nv[e] = lg[e] + (double)bg[e] + (double)noise[(size_t)t * 8 + e] * sp;
    }
    int i0 = 0;
    double v0 = nv[0];
#pragma unroll
    for (int e = 1; e < 8; ++e)
      if (nv[e] > v0) { v0 = nv[e]; i0 = e; }
    int i1 = (i0 == 0) ? 1 : 0;
    double v1 = nv[i0 == 0 ? 1 : 0];
#pragma unroll
    for (int e = 0; e < 8; ++e)
      if (e != i0 && nv[e] > v1) { v1 = nv[e]; i1 = e; }
    if (l == 0) {
      double w1 = exp(v1 - v0);
      double s = 1.0 + w1;
      e0e1[t] = i0 | (i1 << 8);
      gg[t] = make_float2((float)(1.0 / s), (float)(w1 / s));
    }
  } else if (id < 12288) {
    // ---- zero d_out (replaces hipMemsetAsync) ----
    const int b = (id - 10240) * 1024 + tid;
    const float4 z = {0.f, 0.f, 0.f, 0.f};
#pragma unroll
    for (int j = 0; j < 4; ++j) out4[b + j * 256] = z;
  } else {
    // ---- Wd [E][H][D] -> WdT [E][D][H] bf16 (only launched in big-workspace layout) ----
    const int t = id - 12288;
    const int e = t >> 9, rem = t & 511;
    transpose_body(Wd, WdT, HDIM, DDIM, e, rem & 15, rem >> 4, tile);
  }
}

// ---------------- deterministic compaction: 8 blocks (1/expert), 8 waves each ----------------
__global__ __launch_bounds__(512) void compact_kernel(
    const int* __restrict__ e0e1, const float2* __restrict__ gg,
    int* __restrict__ tok_list, float* __restrict__ gate_list,
    int* __restrict__ counts, int* __restrict__ bases) {
  __shared__ int cmat[8][8];  // [wave][expert]
  const int e = blockIdx.x;
  const int wid = threadIdx.x >> 6, l = threadIdx.x & 63;
  const int t0w = wid * (T_TOK / 8);
  int c[8] = {0, 0, 0, 0, 0, 0, 0, 0};
  for (int i = 0; i < T_TOK / 8 / 64; ++i) {
    int p = e0e1[t0w + i * 64 + l];
    int ea = p & 255, eb = (p >> 8) & 255;
#pragma unroll
    for (int ee = 0; ee < 8; ++ee)
      c[ee] += __popcll(__ballot(ea == ee || eb == ee));
  }
  if (l == 0) {
#pragma unroll
    for (int ee = 0; ee < 8; ++ee) cmat[wid][ee] = c[ee];
  }
  __syncthreads();
  int base = 0;
  for (int ee = 0; ee < 8; ++ee) {
    if (ee < e) {
#pragma unroll
      for (int w = 0; w < 8; ++w) base += cmat[w][ee];
    }
  }
  int off = base;
#pragma unroll
  for (int w = 0; w < 8; ++w)
    if (w < wid) off += cmat[w][e];
  if (threadIdx.x == 0) {
    int tot = 0;
#pragma unroll
    for (int w = 0; w < 8; ++w) tot += cmat[w][e];
    counts[e] = tot;
    bases[e] = base;
  }
  for (int i = 0; i < T_TOK / 8 / 64; ++i) {
    int t = t0w + i * 64 + l;
    int p = e0e1[t];
    int ea = p & 255, eb = (p >> 8) & 255;
    int k = (ea == e) ? 0 : ((eb == e) ? 1 : -1);
    unsigned long long m = __ballot(k >= 0);
    if (k >= 0) {
      int pos = __popcll(m & ((1ull << l) - 1ull));
      float2 g = gg[t];
      tok_list[off + pos] = t;
      gate_list[off + pos] = (k == 0) ? g.x : g.y;
    }
    off += __popcll(m);
  }
}

// =====================================================================================
// m97-structure GEMM (round-8 verified best): 128x128 tile, BK=64, 4 waves (2x2, 64x64),
// single 32KB buffer, 2 barriers per K-step, 32 MFMA/wave/K-step,
// chunk^=(row&7) swizzle on BOTH gload-source and ds_read (involution).
// Round-13 change: launch_bounds min-waves 3 -> 4 (up) / 5 (down). LDS/VGPR fit:
//   up 36KB x4 = 144KB <= 160KB, VGPR 68 <= 512/4; down 32KB x5 = 160KB, 68 <= 512/5.
// More co-resident blocks -> more TLP to hide the vmcnt(0) barrier drain.
// =====================================================================================

// ---------------- up GEMM: h = gelu(x_gathered @ Wu + bu) -> bf16 h_ws ----------------
__global__ __launch_bounds__(256, 4) void up_gemm_kernel(
    const unsigned short* __restrict__ xb, const unsigned short* __restrict__ WuT,
    const float* __restrict__ bu, const int* __restrict__ tok_list,
    const int* __restrict__ counts, const int* __restrict__ bases,
    unsigned short* __restrict__ h_ws) {
  const int e = blockIdx.z;
  const int count = counts[e];
  const int tileM = blockIdx.y;
  const int tileN = blockIdx.x;
  if (tileM * 128 >= count) return;
  const int base = bases[e];

  __shared__ char lds[36864];  // [0,16K) A 128x64 bf16 | [16K,32K) B | epilogue reuses 36K

  const int tid = threadIdx.x;
  const int wid = tid >> 6, l = tid & 63;
  const int wr = wid >> 1, wc = wid & 1;
  const int lr = l >> 3, j8 = l & 7;
  const int kc = (j8 ^ lr) << 4;  // pre-swizzled global k-chunk byte (row&7 == lr)
  const int cm1 = count - 1;

  const char* gA[4];
  const char* gB[4];
#pragma unroll
  for (int i = 0; i < 4; ++i) {
    int row = wid * 8 + lr + i * 32;  // 0..127
    int tok = tok_list[base + min(tileM * 128 + row, cm1)];
    gA[i] = (const char*)xb + (size_t)tok * 2048 + kc;
    gB[i] = (const char*)WuT + ((size_t)e * HDIM * DDIM + (size_t)(tileN * 128 + row) * DDIM) * 2 + kc;
  }

  const int fr = l & 15, kg = l >> 4;
  int aoff[4][2], boff[4][2];
#pragma unroll
  for (int m = 0; m < 4; ++m)
#pragma unroll
    for (int kk = 0; kk < 2; ++kk)
      aoff[m][kk] = (wr * 64 + m * 16 + fr) * 128 + ((((kk << 2) | kg) ^ (fr & 7)) << 4);
#pragma unroll
  for (int n = 0; n < 4; ++n)
#pragma unroll
    for (int kk = 0; kk < 2; ++kk)
      boff[n][kk] = 16384 + (wc * 64 + n * 16 + fr) * 128 + ((((kk << 2) | kg) ^ (fr & 7)) << 4);

  f32x4 acc[4][4];
  const f32x4 zz = {0.f, 0.f, 0.f, 0.f};
#pragma unroll
  for (int m = 0; m < 4; ++m)
#pragma unroll
    for (int n = 0; n < 4; ++n) acc[m][n] = zz;

  for (int kt = 0; kt < 16; ++kt) {
    __builtin_amdgcn_s_barrier();  // all waves done reading previous tile
    asm volatile("" ::: "memory");
#pragma unroll
    for (int i = 0; i < 4; ++i)
      __builtin_amdgcn_global_load_lds((as1_cchar*)(gA[i] + kt * 128),
                                       (as3_char*)lds + wid * 1024 + i * 4096, 16, 0, 0);
#pragma unroll
    for (int i = 0; i < 4; ++i)
      __builtin_amdgcn_global_load_lds((as1_cchar*)(gB[i] + kt * 128),
                                       (as3_char*)lds + 16384 + wid * 1024 + i * 4096, 16, 0, 0);
    asm volatile("s_waitcnt vmcnt(0)" ::: "memory");
    __builtin_amdgcn_s_barrier();
    asm volatile("" ::: "memory");

    short8 bf[4][2];
#pragma unroll
    for (int n = 0; n < 4; ++n) {
      bf[n][0] = *(const short8*)(lds + boff[n][0]);
      bf[n][1] = *(const short8*)(lds + boff[n][1]);
    }
    __builtin_amdgcn_s_setprio(1);
#pragma unroll
    for (int m = 0; m < 4; ++m) {
      short8 a0 = *(const short8*)(lds + aoff[m][0]);
      short8 a1 = *(const short8*)(lds + aoff[m][1]);
#pragma unroll
      for (int n = 0; n < 4; ++n) {
        acc[m][n] = __builtin_amdgcn_mfma_f32_16x16x32_bf16(a0, bf[n][0], acc[m][n], 0, 0, 0);
        acc[m][n] = __builtin_amdgcn_mfma_f32_16x16x32_bf16(a1, bf[n][1], acc[m][n], 0, 0, 0);
      }
    }
    __builtin_amdgcn_s_setprio(0);
  }

  // ---- epilogue: gelu -> bf16 -> LDS (stride 144) -> coalesced 16B row stores ----
  __builtin_amdgcn_s_barrier();  // everyone done with GEMM LDS
  asm volatile("" ::: "memory");
  char* epi = lds + wid * 9216;  // 64 rows x 144B per wave
#pragma unroll
  for (int n = 0; n < 4; ++n) {
    const float bv = bu[e * HDIM + tileN * 128 + wc * 64 + n * 16 + fr];
#pragma unroll
    for (int m = 0; m < 4; ++m) {
#pragma unroll
      for (int r = 0; r < 4; ++r) {
        float v = gelu_exact(acc[m][n][r] + bv);
        *(unsigned short*)(epi + (m * 16 + kg * 4 + r) * 144 + (n * 16 + fr) * 2) =
            (unsigned short)f2bf(v);
      }
    }
  }
#pragma unroll
  for (int jj = 0; jj < 8; ++jj) {
    const int row = jj * 8 + lr;
    const int grow = tileM * 128 + wr * 64 + row;
    if (grow < count) {
      uint4 v = *(const uint4*)(epi + row * 144 + j8 * 16);
      *(uint4*)((char*)h_ws +
                ((size_t)(base + grow) * HDIM + tileN * 128 + wc * 64 + j8 * 8) * 2) = v;
    }
  }
}

// ---------------- down GEMM: out += gate * (h @ Wd + bd), atomic scatter ----------------
__global__ __launch_bounds__(256, 5) void down_gemm_kernel(
    const unsigned short* __restrict__ h_ws, const unsigned short* __restrict__ WdT,
    const float* __restrict__ bd, const int* __restrict__ tok_list,
    const float* __restrict__ gate_list, const int* __restrict__ counts,
    const int* __restrict__ bases, float* __restrict__ out) {
  const int e = blockIdx.z;
  const int count = counts[e];
  const int tileM = blockIdx.y;
  const int tileN = blockIdx.x;
  if (tileM * 128 >= count) return;
  const int base = bases[e];

  __shared__ char lds[32768];

  const int tid = threadIdx.x;
  const int wid = tid >> 6, l = tid & 63;
  const int wr = wid >> 1, wc = wid & 1;
  const int lr = l >> 3, j8 = l & 7;
  const int kc = (j8 ^ lr) << 4;
  const int cm1 = count - 1;

  const char* gA[4];
  const char* gB[4];
#pragma unroll
  for (int i = 0; i < 4; ++i) {
    int row = wid * 8 + lr + i * 32;
    gA[i] = (const char*)h_ws + (size_t)(base + min(tileM * 128 + row, cm1)) * 4096 + kc;
    gB[i] = (const char*)WdT + ((size_t)e * DDIM * HDIM + (size_t)(tileN * 128 + row) * HDIM) * 2 + kc;
  }

  const int fr = l & 15, kg = l >> 4;
  int aoff[4][2], boff[4][2];
#pragma unroll
  for (int m = 0; m < 4; ++m)
#pragma unroll
    for (int kk = 0; kk < 2; ++kk)
      aoff[m][kk] = (wr * 64 + m * 16 + fr) * 128 + ((((kk << 2) | kg) ^ (fr & 7)) << 4);
#pragma unroll
  for (int n = 0; n < 4; ++n)
#pragma unroll
    for (int kk = 0; kk < 2; ++kk)
      boff[n][kk] = 16384 + (wc * 64 + n * 16 + fr) * 128 + ((((kk << 2) | kg) ^ (fr & 7)) << 4);

  f32x4 acc[4][4];
  const f32x4 zz = {0.f, 0.f, 0.f, 0.f};
#pragma unroll
  for (int m = 0; m < 4; ++m)
#pragma unroll
    for (int n = 0; n < 4; ++n) acc[m][n] = zz;

  for (int kt = 0; kt < 32; ++kt) {
    __builtin_amdgcn_s_barrier();
    asm volatile("" ::: "memory");
#pragma unroll
    for (int i = 0; i < 4; ++i)
      __builtin_amdgcn_global_load_lds((as1_cchar*)(gA[i] + kt * 128),
                                       (as3_char*)lds + wid * 1024 + i * 4096, 16, 0, 0);
#pragma unroll
    for (int i = 0; i < 4; ++i)
      __builtin_amdgcn_global_load_lds((as1_cchar*)(gB[i] + kt * 128),
                                       (as3_char*)lds + 16384 + wid * 1024 + i * 4096, 16, 0, 0);
    asm volatile("s_waitcnt vmcnt(0)" ::: "memory");
    __builtin_amdgcn_s_barrier();
    asm volatile("" ::: "memory");

    short8 bf[4][2];
#pragma unroll
    for (int n = 0; n < 4; ++n) {
      bf[n][0] = *(const short8*)(lds + boff[n][0]);
      bf[n][1] = *(const short8*)(lds + boff[n][1]);
    }
    __builtin_amdgcn_s_setprio(1);
#pragma unroll
    for (int m = 0; m < 4; ++m) {
      short8 a0 = *(const short8*)(lds + aoff[m][0]);
      short8 a1 = *(const short8*)(lds + aoff[m][1]);
#pragma unroll
      for (int n = 0; n < 4; ++n) {
        acc[m][n] = __builtin_amdgcn_mfma_f32_16x16x32_bf16(a0, bf[n][0], acc[m][n], 0, 0, 0);
        acc[m][n] = __builtin_amdgcn_mfma_f32_16x16x32_bf16(a1, bf[n][1], acc[m][n], 0, 0, 0);
      }
    }
    __builtin_amdgcn_s_setprio(0);
  }

  const int colBase = tileN * 128;
  float bdv[4];
#pragma unroll
  for (int n = 0; n < 4; ++n) bdv[n] = bd[e * DDIM + colBase + wc * 64 + n * 16 + fr];
#pragma unroll
  for (int m = 0; m < 4; ++m) {
#pragma unroll
    for (int r = 0; r < 4; ++r) {
      const int sl = tileM * 128 + wr * 64 + m * 16 + kg * 4 + r;
      if (sl < count) {
        const int idx = base + sl;
        const float gate = gate_list[idx];
        const int tok = tok_list[idx];
        float* orow = out + (size_t)tok * DDIM + colBase;
#pragma unroll
        for (int n = 0; n < 4; ++n) {
          const int col = wc * 64 + n * 16 + fr;
          atomicAdd(orow + col, (acc[m][n][r] + bdv[n]) * gate);
        }
      }
    }
  }
}

// ---------------- host launcher ----------------
// Layout A (ws_size >= 151,781,376 B): WdT gets its own region; Wd transpose fused in prep.
//   xb [0,16M) | WuT [16M,48M) | hws [48M,117.96M) | WdT [117.96M,151.5M) | small
// Layout B (fallback = round-11): WdT reuses [0,32M) after up_gemm; separate transpose.
extern "C" void kernel_launch(void* const* d_in, const int* in_sizes, int n_in,
                              void* d_out, int out_size, void* d_ws, size_t ws_size,
                              hipStream_t stream) {
  const float* x     = (const float*)d_in[0];
  const float* noise = (const float*)d_in[1];
  const float* Wg    = (const float*)d_in[2];
  const float* bg    = (const float*)d_in[3];
  const float* Wn    = (const float*)d_in[4];
  const float* bn    = (const float*)d_in[5];
  const float* Wu    = (const float*)d_in[6];
  const float* bu    = (const float*)d_in[7];
  const float* Wd    = (const float*)d_in[8];
  const float* bd    = (const float*)d_in[9];
  float* out = (float*)d_out;
  char* ws = (char*)d_ws;

  const bool bigws = (ws_size >= 151781376ull);

  unsigned short* xb  = (unsigned short*)(ws);                    // 16,777,216 B
  unsigned short* WuT = (unsigned short*)(ws + 16777216);         // 33,554,432 B
  unsigned short* hws = (unsigned short*)(ws + 50331648);         // 67,633,152 B
  unsigned short* WdT = bigws ? (unsigned short*)(ws + 117964800)  // own 32MB region
                              : (unsigned short*)(ws);             // reuse (after up_gemm)
  char* small = bigws ? (ws + 151519232) : (ws + 117964800);
  int*    e0e1      = (int*)(small);                              // 32,768 B
  float2* gg        = (float2*)(small + 32768);                   // 65,536 B
  int*    tok_list  = (int*)(small + 98304);                      // 65,536 B
  float*  gate_list = (float*)(small + 163840);                   // 65,536 B
  int*    counts    = (int*)(small + 229376);
  int*    bases     = (int*)(small + 229408);

  // prep: 4096 cast_x + 4096 trWu + 2048 router + 2048 zero-out [+ 4096 trWd if bigws]
  const int prep_blocks = bigws ? 16384 : 12288;
  prep_kernel<<<prep_blocks, 256, 0, stream>>>(x, noise, Wg, bg, Wn, bn, Wu, Wd,
                                               xb, WuT, WdT, e0e1, gg, (float4*)out);
  compact_kernel<<<NE, 512, 0, stream>>>(e0e1, gg, tok_list, gate_list, counts, bases);
  up_gemm_kernel<<<dim3(16, 64, NE), 256, 0, stream>>>(xb, WuT, bu, tok_list, counts, bases, hws);
  if (!bigws)
    transpose_cast64<<<dim3(DDIM / 64, HDIM / 64, NE), 256, 0, stream>>>(Wd, WdT, HDIM, DDIM);
  down_gemm_kernel<<<dim3(8, 64, NE), 256, 0, stream>>>(hws, WdT, bd, tok_list, gate_list, counts, bases, out);
}

// Round 14
// 323.747 us; speedup vs baseline: 1.8822x; 1.8822x over previous
//
#include <hip/hip_runtime.h>
#include <math.h>

#define T_TOK 8192
#define DDIM 1024
#define HDIM 2048
#define NE 8

typedef float f32x4 __attribute__((ext_vector_type(4)));
typedef short short8 __attribute__((ext_vector_type(8)));
typedef __attribute__((address_space(3))) char as3_char;
typedef __attribute__((address_space(1))) const char as1_cchar;

__device__ __forceinline__ unsigned f2bf(float f) {
  unsigned u = __float_as_uint(f);
  return (u + 0x7fffu + ((u >> 16) & 1u)) >> 16;
}
__device__ __forceinline__ float gelu_exact(float v) {
  return 0.5f * v * (1.0f + erff(v * 0.70710678118654752f));
}

// ---------------- transpose + cast: in [E][R][C] f32 -> out [E][C][R] bf16, 64x64 tiles ----
__device__ __forceinline__ void transpose_body(const float* __restrict__ in,
                                               unsigned short* __restrict__ out,
                                               int R, int C, int e, int bx, int by,
                                               float (*tile)[65]) {
  size_t eoff = (size_t)e * R * C;
  const int r0 = by << 6, c0 = bx << 6;
  const int tid = threadIdx.x;
  const int lr = tid >> 4;          // 0..15
  const int lc4 = (tid & 15) << 2;  // 0,4,..,60
#pragma unroll
  for (int rr = 0; rr < 4; ++rr) {
    int r = lr + rr * 16;
    float4 v = *(const float4*)(in + eoff + (size_t)(r0 + r) * C + c0 + lc4);
    tile[r][lc4] = v.x; tile[r][lc4 + 1] = v.y; tile[r][lc4 + 2] = v.z; tile[r][lc4 + 3] = v.w;
  }
  __syncthreads();
  const int c = tid >> 2;           // 0..63
  const int rch = (tid & 3) << 4;   // 0,16,32,48
  unsigned short tmp[16];
#pragma unroll
  for (int i = 0; i < 16; ++i) tmp[i] = (unsigned short)f2bf(tile[rch + i][c]);
  unsigned short* dst = out + eoff + (size_t)(c0 + c) * R + r0 + rch;
  *(uint4*)dst = *(const uint4*)tmp;
  *(uint4*)(dst + 8) = *(const uint4*)(tmp + 8);
}

// standalone transpose kernel (fallback path: Wd after up_gemm frees the region)
__global__ __launch_bounds__(256) void transpose_cast64(const float* __restrict__ in,
                                                        unsigned short* __restrict__ out,
                                                        int R, int C) {
  __shared__ float tile[64][65];
  transpose_body(in, out, R, C, blockIdx.z, blockIdx.x, blockIdx.y, tile);
}

// ---------------- fused prep: cast_x | Wu-transpose | router | zero-out | [Wd-transpose] ----
__global__ __launch_bounds__(256) void prep_kernel(
    const float* __restrict__ x, const float* __restrict__ noise,
    const float* __restrict__ Wg, const float* __restrict__ bg,
    const float* __restrict__ Wn, const float* __restrict__ bn,
    const float* __restrict__ Wu, const float* __restrict__ Wd,
    unsigned short* __restrict__ xb, unsigned short* __restrict__ WuT,
    unsigned short* __restrict__ WdT,
    int* __restrict__ e0e1, float2* __restrict__ gg, float4* __restrict__ out4) {
  __shared__ float tile[64][65];
  const int id = blockIdx.x;
  const int tid = threadIdx.x;

  if (id < 4096) {
    // ---- cast x -> bf16 ----
    const int i = id * 256 + tid;
    const float4* x4 = (const float4*)x;
    float4 a = x4[2 * i], b = x4[2 * i + 1];
    uint4 o;
    o.x = f2bf(a.x) | (f2bf(a.y) << 16);
    o.y = f2bf(a.z) | (f2bf(a.w) << 16);
    o.z = f2bf(b.x) | (f2bf(b.y) << 16);
    o.w = f2bf(b.z) | (f2bf(b.w) << 16);
    ((uint4*)xb)[i] = o;
  } else if (id < 8192) {
    // ---- Wu [E][D][H] -> WuT [E][H][D] bf16 ----
    const int t = id - 4096;
    const int e = t >> 9, rem = t & 511;
    transpose_body(Wu, WuT, DDIM, HDIM, e, rem & 31, rem >> 5, tile);
  } else if (id < 10240) {
    // ---- router: 4 tokens/block, wave per token, fp64 dots on NATURAL Wg/Wn ----
    const int wid = tid >> 6, l = tid & 63;
    const int t = (id - 8192) * 4 + wid;
    double lg[8] = {0, 0, 0, 0, 0, 0, 0, 0}, ln[8] = {0, 0, 0, 0, 0, 0, 0, 0};
    const float* xp = x + (size_t)t * DDIM;
#pragma unroll
    for (int i = 0; i < 16; ++i) {
      int d = i * 64 + l;
      float xv = xp[d];
      const float4* w4 = (const float4*)(Wg + d * 8);
      float4 wa = w4[0], wb = w4[1];
      lg[0] += (double)xv * wa.x; lg[1] += (double)xv * wa.y;
      lg[2] += (double)xv * wa.z; lg[3] += (double)xv * wa.w;
      lg[4] += (double)xv * wb.x; lg[5] += (double)xv * wb.y;
      lg[6] += (double)xv * wb.z; lg[7] += (double)xv * wb.w;
      const float4* n4 = (const float4*)(Wn + d * 8);
      float4 na = n4[0], nb = n4[1];
      ln[0] += (double)xv * na.x; ln[1] += (double)xv * na.y;
      ln[2] += (double)xv * na.z; ln[3] += (double)xv * na.w;
      ln[4] += (double)xv * nb.x; ln[5] += (double)xv * nb.y;
      ln[6] += (double)xv * nb.z; ln[7] += (double)xv * nb.w;
    }
#pragma unroll
    for (int e = 0; e < 8; ++e) {
#pragma unroll
      for (int off = 1; off < 64; off <<= 1) {
        lg[e] += __shfl_xor(lg[e], off);
        ln[e] += __shfl_xor(ln[e], off);
      }
    }
    double nv[8];
#pragma unroll
    for (int e = 0; e < 8; ++e) {
      double nl = ln[e] + (double)bn[e];
      double sp = (nl > 30.0) ? nl : log1p(exp(nl));
      nv[e] = lg[e] + (double)bg[e] + (double)noise[(size_t)t * 8 + e] * sp;
    }
    int i0 = 0;
    double v0 = nv[0];
#pragma unroll
    for (int e = 1; e < 8; ++e)
      if (nv[e] > v0) { v0 = nv[e]; i0 = e; }
    int i1 = (i0 == 0) ? 1 : 0;
    double v1 = nv[i0 == 0 ? 1 : 0];
#pragma unroll
    for (int e = 0; e < 8; ++e)
      if (e != i0 && nv[e] > v1) { v1 = nv[e]; i1 = e; }
    if (l == 0) {
      double w1 = exp(v1 - v0);
      double s = 1.0 + w1;
      e0e1[t] = i0 | (i1 << 8);
      gg[t] = make_float2((float)(1.0 / s), (float)(w1 / s));
    }
  } else if (id < 12288) {
    // ---- zero d_out (replaces hipMemsetAsync) ----
    const int b = (id - 10240) * 1024 + tid;
    const float4 z = {0.f, 0.f, 0.f, 0.f};
#pragma unroll
    for (int j = 0; j < 4; ++j) out4[b + j * 256] = z;
  } else {
    // ---- Wd [E][H][D] -> WdT [E][D][H] bf16 (only launched in big-workspace layout) ----
    const int t = id - 12288;
    const int e = t >> 9, rem = t & 511;
    transpose_body(Wd, WdT, HDIM, DDIM, e, rem & 15, rem >> 4, tile);
  }
}

// ---------------- deterministic compaction: 8 blocks (1/expert), 8 waves each ----------------
__global__ __launch_bounds__(512) void compact_kernel(
    const int* __restrict__ e0e1, const float2* __restrict__ gg,
    int* __restrict__ tok_list, float* __restrict__ gate_list,
    int* __restrict__ counts, int* __restrict__ bases) {
  __shared__ int cmat[8][8];  // [wave][expert]
  const int e = blockIdx.x;
  const int wid = threadIdx.x >> 6, l = threadIdx.x & 63;
  const int t0w = wid * (T_TOK / 8);
  int c[8] = {0, 0, 0, 0, 0, 0, 0, 0};
  for (int i = 0; i < T_TOK / 8 / 64; ++i) {
    int p = e0e1[t0w + i * 64 + l];
    int ea = p & 255, eb = (p >> 8) & 255;
#pragma unroll
    for (int ee = 0; ee < 8; ++ee)
      c[ee] += __popcll(__ballot(ea == ee || eb == ee));
  }
  if (l == 0) {
#pragma unroll
    for (int ee = 0; ee < 8; ++ee) cmat[wid][ee] = c[ee];
  }
  __syncthreads();
  int base = 0;
  for (int ee = 0; ee < 8; ++ee) {
    if (ee < e) {
#pragma unroll
      for (int w = 0; w < 8; ++w) base += cmat[w][ee];
    }
  }
  int off = base;
#pragma unroll
  for (int w = 0; w < 8; ++w)
    if (w < wid) off += cmat[w][e];
  if (threadIdx.x == 0) {
    int tot = 0;
#pragma unroll
    for (int w = 0; w < 8; ++w) tot += cmat[w][e];
    counts[e] = tot;
    bases[e] = base;
  }
  for (int i = 0; i < T_TOK / 8 / 64; ++i) {
    int t = t0w + i * 64 + l;
    int p = e0e1[t];
    int ea = p & 255, eb = (p >> 8) & 255;
    int k = (ea == e) ? 0 : ((eb == e) ? 1 : -1);
    unsigned long long m = __ballot(k >= 0);
    if (k >= 0) {
      int pos = __popcll(m & ((1ull << l) - 1ull));
      float2 g = gg[t];
      tok_list[off + pos] = t;
      gate_list[off + pos] = (k == 0) ? g.x : g.y;
    }
    off += __popcll(m);
  }
}

// =====================================================================================
// m97-structure GEMM: 128x128 tile, BK=64, 4 waves (2x2, 64x64), single 32KB buffer,
// 2 barriers per K-step, chunk^=(row&7) swizzle both sides.
// launch_bounds (256,4): min 4 waves/EU -> VGPR cap 128 >= 68 used (NO spill; the
// round-13 (256,5) variant capped at 48 and spilled acc -> WRITE_SIZE 329MB, 3.4x slower).
// LDS fit at 4 blocks/CU: up 4x36KB=144 <= 160KB, down 4x32KB=128 <= 160KB.
// =====================================================================================

// ---------------- up GEMM: h = gelu(x_gathered @ Wu + bu) -> bf16 h_ws ----------------
__global__ __launch_bounds__(256, 4) void up_gemm_kernel(
    const unsigned short* __restrict__ xb, const unsigned short* __restrict__ WuT,
    const float* __restrict__ bu, const int* __restrict__ tok_list,
    const int* __restrict__ counts, const int* __restrict__ bases,
    unsigned short* __restrict__ h_ws) {
  const int e = blockIdx.z;
  const int count = counts[e];
  const int tileM = blockIdx.y;
  const int tileN = blockIdx.x;
  if (tileM * 128 >= count) return;
  const int base = bases[e];

  __shared__ char lds[36864];  // [0,16K) A 128x64 bf16 | [16K,32K) B | epilogue reuses 36K

  const int tid = threadIdx.x;
  const int wid = tid >> 6, l = tid & 63;
  const int wr = wid >> 1, wc = wid & 1;
  const int lr = l >> 3, j8 = l & 7;
  const int kc = (j8 ^ lr) << 4;  // pre-swizzled global k-chunk byte (row&7 == lr)
  const int cm1 = count - 1;

  const char* gA[4];
  const char* gB[4];
#pragma unroll
  for (int i = 0; i < 4; ++i) {
    int row = wid * 8 + lr + i * 32;  // 0..127
    int tok = tok_list[base + min(tileM * 128 + row, cm1)];
    gA[i] = (const char*)xb + (size_t)tok * 2048 + kc;
    gB[i] = (const char*)WuT + ((size_t)e * HDIM * DDIM + (size_t)(tileN * 128 + row) * DDIM) * 2 + kc;
  }

  const int fr = l & 15, kg = l >> 4;
  int aoff[4][2], boff[4][2];
#pragma unroll
  for (int m = 0; m < 4; ++m)
#pragma unroll
    for (int kk = 0; kk < 2; ++kk)
      aoff[m][kk] = (wr * 64 + m * 16 + fr) * 128 + ((((kk << 2) | kg) ^ (fr & 7)) << 4);
#pragma unroll
  for (int n = 0; n < 4; ++n)
#pragma unroll
    for (int kk = 0; kk < 2; ++kk)
      boff[n][kk] = 16384 + (wc * 64 + n * 16 + fr) * 128 + ((((kk << 2) | kg) ^ (fr & 7)) << 4);

  f32x4 acc[4][4];
  const f32x4 zz = {0.f, 0.f, 0.f, 0.f};
#pragma unroll
  for (int m = 0; m < 4; ++m)
#pragma unroll
    for (int n = 0; n < 4; ++n) acc[m][n] = zz;

  for (int kt = 0; kt < 16; ++kt) {
    __builtin_amdgcn_s_barrier();  // all waves done reading previous tile
    asm volatile("" ::: "memory");
#pragma unroll
    for (int i = 0; i < 4; ++i)
      __builtin_amdgcn_global_load_lds((as1_cchar*)(gA[i] + kt * 128),
                                       (as3_char*)lds + wid * 1024 + i * 4096, 16, 0, 0);
#pragma unroll
    for (int i = 0; i < 4; ++i)
      __builtin_amdgcn_global_load_lds((as1_cchar*)(gB[i] + kt * 128),
                                       (as3_char*)lds + 16384 + wid * 1024 + i * 4096, 16, 0, 0);
    asm volatile("s_waitcnt vmcnt(0)" ::: "memory");
    __builtin_amdgcn_s_barrier();
    asm volatile("" ::: "memory");

    short8 bf[4][2];
#pragma unroll
    for (int n = 0; n < 4; ++n) {
      bf[n][0] = *(const short8*)(lds + boff[n][0]);
      bf[n][1] = *(const short8*)(lds + boff[n][1]);
    }
    __builtin_amdgcn_s_setprio(1);
#pragma unroll
    for (int m = 0; m < 4; ++m) {
      short8 a0 = *(const short8*)(lds + aoff[m][0]);
      short8 a1 = *(const short8*)(lds + aoff[m][1]);
#pragma unroll
      for (int n = 0; n < 4; ++n) {
        acc[m][n] = __builtin_amdgcn_mfma_f32_16x16x32_bf16(a0, bf[n][0], acc[m][n], 0, 0, 0);
        acc[m][n] = __builtin_amdgcn_mfma_f32_16x16x32_bf16(a1, bf[n][1], acc[m][n], 0, 0, 0);
      }
    }
    __builtin_amdgcn_s_setprio(0);
  }

  // ---- epilogue: gelu -> bf16 -> LDS (stride 144) -> coalesced 16B row stores ----
  __builtin_amdgcn_s_barrier();  // everyone done with GEMM LDS
  asm volatile("" ::: "memory");
  char* epi = lds + wid * 9216;  // 64 rows x 144B per wave
#pragma unroll
  for (int n = 0; n < 4; ++n) {
    const float bv = bu[e * HDIM + tileN * 128 + wc * 64 + n * 16 + fr];
#pragma unroll
    for (int m = 0; m < 4; ++m) {
#pragma unroll
      for (int r = 0; r < 4; ++r) {
        float v = gelu_exact(acc[m][n][r] + bv);
        *(unsigned short*)(epi + (m * 16 + kg * 4 + r) * 144 + (n * 16 + fr) * 2) =
            (unsigned short)f2bf(v);
      }
    }
  }
#pragma unroll
  for (int jj = 0; jj < 8; ++jj) {
    const int row = jj * 8 + lr;
    const int grow = tileM * 128 + wr * 64 + row;
    if (grow < count) {
      uint4 v = *(const uint4*)(epi + row * 144 + j8 * 16);
      *(uint4*)((char*)h_ws +
                ((size_t)(base + grow) * HDIM + tileN * 128 + wc * 64 + j8 * 8) * 2) = v;
    }
  }
}

// ---------------- down GEMM: out += gate * (h @ Wd + bd), atomic scatter ----------------
__global__ __launch_bounds__(256, 4) void down_gemm_kernel(
    const unsigned short* __restrict__ h_ws, const unsigned short* __restrict__ WdT,
    const float* __restrict__ bd, const int* __restrict__ tok_list,
    const float* __restrict__ gate_list, const int* __restrict__ counts,
    const int* __restrict__ bases, float* __restrict__ out) {
  const int e = blockIdx.z;
  const int count = counts[e];
  const int tileM = blockIdx.y;
  const int tileN = blockIdx.x;
  if (tileM * 128 >= count) return;
  const int base = bases[e];

  __shared__ char lds[32768];

  const int tid = threadIdx.x;
  const int wid = tid >> 6, l = tid & 63;
  const int wr = wid >> 1, wc = wid & 1;
  const int lr = l >> 3, j8 = l & 7;
  const int kc = (j8 ^ lr) << 4;
  const int cm1 = count - 1;

  const char* gA[4];
  const char* gB[4];
#pragma unroll
  for (int i = 0; i < 4; ++i) {
    int row = wid * 8 + lr + i * 32;
    gA[i] = (const char*)h_ws + (size_t)(base + min(tileM * 128 + row, cm1)) * 4096 + kc;
    gB[i] = (const char*)WdT + ((size_t)e * DDIM * HDIM + (size_t)(tileN * 128 + row) * HDIM) * 2 + kc;
  }

  const int fr = l & 15, kg = l >> 4;
  int aoff[4][2], boff[4][2];
#pragma unroll
  for (int m = 0; m < 4; ++m)
#pragma unroll
    for (int kk = 0; kk < 2; ++kk)
      aoff[m][kk] = (wr * 64 + m * 16 + fr) * 128 + ((((kk << 2) | kg) ^ (fr & 7)) << 4);
#pragma unroll
  for (int n = 0; n < 4; ++n)
#pragma unroll
    for (int kk = 0; kk < 2; ++kk)
      boff[n][kk] = 16384 + (wc * 64 + n * 16 + fr) * 128 + ((((kk << 2) | kg) ^ (fr & 7)) << 4);

  f32x4 acc[4][4];
  const f32x4 zz = {0.f, 0.f, 0.f, 0.f};
#pragma unroll
  for (int m = 0; m < 4; ++m)
#pragma unroll
    for (int n = 0; n < 4; ++n) acc[m][n] = zz;

  for (int kt = 0; kt < 32; ++kt) {
    __builtin_amdgcn_s_barrier();
    asm volatile("" ::: "memory");
#pragma unroll
    for (int i = 0; i < 4; ++i)
      __builtin_amdgcn_global_load_lds((as1_cchar*)(gA[i] + kt * 128),
                                       (as3_char*)lds + wid * 1024 + i * 4096, 16, 0, 0);
#pragma unroll
    for (int i = 0; i < 4; ++i)
      __builtin_amdgcn_global_load_lds((as1_cchar*)(gB[i] + kt * 128),
                                       (as3_char*)lds + 16384 + wid * 1024 + i * 4096, 16, 0, 0);
    asm volatile("s_waitcnt vmcnt(0)" ::: "memory");
    __builtin_amdgcn_s_barrier();
    asm volatile("" ::: "memory");

    short8 bf[4][2];
#pragma unroll
    for (int n = 0; n < 4; ++n) {
      bf[n][0] = *(const short8*)(lds + boff[n][0]);
      bf[n][1] = *(const short8*)(lds + boff[n][1]);
    }
    __builtin_amdgcn_s_setprio(1);
#pragma unroll
    for (int m = 0; m < 4; ++m) {
      short8 a0 = *(const short8*)(lds + aoff[m][0]);
      short8 a1 = *(const short8*)(lds + aoff[m][1]);
#pragma unroll
      for (int n = 0; n < 4; ++n) {
        acc[m][n] = __builtin_amdgcn_mfma_f32_16x16x32_bf16(a0, bf[n][0], acc[m][n], 0, 0, 0);
        acc[m][n] = __builtin_amdgcn_mfma_f32_16x16x32_bf16(a1, bf[n][1], acc[m][n], 0, 0, 0);
      }
    }
    __builtin_amdgcn_s_setprio(0);
  }

  const int colBase = tileN * 128;
  float bdv[4];
#pragma unroll
  for (int n = 0; n < 4; ++n) bdv[n] = bd[e * DDIM + colBase + wc * 64 + n * 16 + fr];
#pragma unroll
  for (int m = 0; m < 4; ++m) {
#pragma unroll
    for (int r = 0; r < 4; ++r) {
      const int sl = tileM * 128 + wr * 64 + m * 16 + kg * 4 + r;
      if (sl < count) {
        const int idx = base + sl;
        const float gate = gate_list[idx];
        const int tok = tok_list[idx];
        float* orow = out + (size_t)tok * DDIM + colBase;
#pragma unroll
        for (int n = 0; n < 4; ++n) {
          const int col = wc * 64 + n * 16 + fr;
          atomicAdd(orow + col, (acc[m][n][r] + bdv[n]) * gate);
        }
      }
    }
  }
}

// ---------------- host launcher ----------------
// Layout A (ws_size >= 151,781,376 B): WdT gets its own region; Wd transpose fused in prep.
//   xb [0,16M) | WuT [16M,48M) | hws [48M,117.96M) | WdT [117.96M,151.5M) | small
// Layout B (fallback): WdT reuses [0,32M) after up_gemm; separate transpose.
extern "C" void kernel_launch(void* const* d_in, const int* in_sizes, int n_in,
                              void* d_out, int out_size, void* d_ws, size_t ws_size,
                              hipStream_t stream) {
  const float* x     = (const float*)d_in[0];
  const float* noise = (const float*)d_in[1];
  const float* Wg    = (const float*)d_in[2];
  const float* bg    = (const float*)d_in[3];
  const float* Wn    = (const float*)d_in[4];
  const float* bn    = (const float*)d_in[5];
  const float* Wu    = (const float*)d_in[6];
  const float* bu    = (const float*)d_in[7];
  const float* Wd    = (const float*)d_in[8];
  const float* bd    = (const float*)d_in[9];
  float* out = (float*)d_out;
  char* ws = (char*)d_ws;

  const bool bigws = (ws_size >= 151781376ull);

  unsigned short* xb  = (unsigned short*)(ws);                    // 16,777,216 B
  unsigned short* WuT = (unsigned short*)(ws + 16777216);         // 33,554,432 B
  unsigned short* hws = (unsigned short*)(ws + 50331648);         // 67,633,152 B
  unsigned short* WdT = bigws ? (unsigned short*)(ws + 117964800)  // own 32MB region
                              : (unsigned short*)(ws);             // reuse (after up_gemm)
  char* small = bigws ? (ws + 151519232) : (ws + 117964800);
  int*    e0e1      = (int*)(small);                              // 32,768 B
  float2* gg        = (float2*)(small + 32768);                   // 65,536 B
  int*    tok_list  = (int*)(small + 98304);                      // 65,536 B
  float*  gate_list = (float*)(small + 163840);                   // 65,536 B
  int*    counts    = (int*)(small + 229376);
  int*    bases     = (int*)(small + 229408);

  // prep: 4096 cast_x + 4096 trWu + 2048 router + 2048 zero-out [+ 4096 trWd if bigws]
  const int prep_blocks = bigws ? 16384 : 12288;
  prep_kernel<<<prep_blocks, 256, 0, stream>>>(x, noise, Wg, bg, Wn, bn, Wu, Wd,
                                               xb, WuT, WdT, e0e1, gg, (float4*)out);
  compact_kernel<<<NE, 512, 0, stream>>>(e0e1, gg, tok_list, gate_list, counts, bases);
  up_gemm_kernel<<<dim3(16, 64, NE), 256, 0, stream>>>(xb, WuT, bu, tok_list, counts, bases, hws);
  if (!bigws)
    transpose_cast64<<<dim3(DDIM / 64, HDIM / 64, NE), 256, 0, stream>>>(Wd, WdT, HDIM, DDIM);
  down_gemm_kernel<<<dim3(8, 64, NE), 256, 0, stream>>>(hws, WdT, bd, tok_list, gate_list, counts, bases, out);
}

// Round 15
// 317.846 us; speedup vs baseline: 1.9171x; 1.0186x over previous
//
#include <hip/hip_runtime.h>
#include <math.h>

#define T_TOK 8192
#define DDIM 1024
#define HDIM 2048
#define NE 8

typedef float f32x4 __attribute__((ext_vector_type(4)));
typedef short short8 __attribute__((ext_vector_type(8)));
typedef __attribute__((address_space(3))) char as3_char;
typedef __attribute__((address_space(1))) const char as1_cchar;

__device__ __forceinline__ unsigned f2bf(float f) {
  unsigned u = __float_as_uint(f);
  return (u + 0x7fffu + ((u >> 16) & 1u)) >> 16;
}
__device__ __forceinline__ float gelu_exact(float v) {
  return 0.5f * v * (1.0f + erff(v * 0.70710678118654752f));
}

// ---------------- transpose + cast: in [E][R][C] f32 -> out [E][C][R] bf16, 64x64 tiles ----
__device__ __forceinline__ void transpose_body(const float* __restrict__ in,
                                               unsigned short* __restrict__ out,
                                               int R, int C, int e, int bx, int by,
                                               float (*tile)[65]) {
  size_t eoff = (size_t)e * R * C;
  const int r0 = by << 6, c0 = bx << 6;
  const int tid = threadIdx.x;
  const int lr = tid >> 4;          // 0..15
  const int lc4 = (tid & 15) << 2;  // 0,4,..,60
#pragma unroll
  for (int rr = 0; rr < 4; ++rr) {
    int r = lr + rr * 16;
    float4 v = *(const float4*)(in + eoff + (size_t)(r0 + r) * C + c0 + lc4);
    tile[r][lc4] = v.x; tile[r][lc4 + 1] = v.y; tile[r][lc4 + 2] = v.z; tile[r][lc4 + 3] = v.w;
  }
  __syncthreads();
  const int c = tid >> 2;           // 0..63
  const int rch = (tid & 3) << 4;   // 0,16,32,48
  unsigned short tmp[16];
#pragma unroll
  for (int i = 0; i < 16; ++i) tmp[i] = (unsigned short)f2bf(tile[rch + i][c]);
  unsigned short* dst = out + eoff + (size_t)(c0 + c) * R + r0 + rch;
  *(uint4*)dst = *(const uint4*)tmp;
  *(uint4*)(dst + 8) = *(const uint4*)(tmp + 8);
}

// standalone transpose kernel (fallback path: Wd after up_gemm frees the region)
__global__ __launch_bounds__(256) void transpose_cast64(const float* __restrict__ in,
                                                        unsigned short* __restrict__ out,
                                                        int R, int C) {
  __shared__ float tile[64][65];
  transpose_body(in, out, R, C, blockIdx.z, blockIdx.x, blockIdx.y, tile);
}

// ---------------- fused prep: cast_x | Wu-transpose | router | zero-out | [Wd-transpose] ----
__global__ __launch_bounds__(256) void prep_kernel(
    const float* __restrict__ x, const float* __restrict__ noise,
    const float* __restrict__ Wg, const float* __restrict__ bg,
    const float* __restrict__ Wn, const float* __restrict__ bn,
    const float* __restrict__ Wu, const float* __restrict__ Wd,
    unsigned short* __restrict__ xb, unsigned short* __restrict__ WuT,
    unsigned short* __restrict__ WdT,
    int* __restrict__ e0e1, float2* __restrict__ gg, float4* __restrict__ out4) {
  __shared__ float tile[64][65];
  const int id = blockIdx.x;
  const int tid = threadIdx.x;

  if (id < 4096) {
    // ---- cast x -> bf16 ----
    const int i = id * 256 + tid;
    const float4* x4 = (const float4*)x;
    float4 a = x4[2 * i], b = x4[2 * i + 1];
    uint4 o;
    o.x = f2bf(a.x) | (f2bf(a.y) << 16);
    o.y = f2bf(a.z) | (f2bf(a.w) << 16);
    o.z = f2bf(b.x) | (f2bf(b.y) << 16);
    o.w = f2bf(b.z) | (f2bf(b.w) << 16);
    ((uint4*)xb)[i] = o;
  } else if (id < 8192) {
    // ---- Wu [E][D][H] -> WuT [E][H][D] bf16 ----
    const int t = id - 4096;
    const int e = t >> 9, rem = t & 511;
    transpose_body(Wu, WuT, DDIM, HDIM, e, rem & 31, rem >> 5, tile);
  } else if (id < 10240) {
    // ---- router: 4 tokens/block, wave per token, fp64 dots on NATURAL Wg/Wn ----
    const int wid = tid >> 6, l = tid & 63;
    const int t = (id - 8192) * 4 + wid;
    double lg[8] = {0, 0, 0, 0, 0, 0, 0, 0}, ln[8] = {0, 0, 0, 0, 0, 0, 0, 0};
    const float* xp = x + (size_t)t * DDIM;
#pragma unroll
    for (int i = 0; i < 16; ++i) {
      int d = i * 64 + l;
      float xv = xp[d];
      const float4* w4 = (const float4*)(Wg + d * 8);
      float4 wa = w4[0], wb = w4[1];
      lg[0] += (double)xv * wa.x; lg[1] += (double)xv * wa.y;
      lg[2] += (double)xv * wa.z; lg[3] += (double)xv * wa.w;
      lg[4] += (double)xv * wb.x; lg[5] += (double)xv * wb.y;
      lg[6] += (double)xv * wb.z; lg[7] += (double)xv * wb.w;
      const float4* n4 = (const float4*)(Wn + d * 8);
      float4 na = n4[0], nb = n4[1];
      ln[0] += (double)xv * na.x; ln[1] += (double)xv * na.y;
      ln[2] += (double)xv * na.z; ln[3] += (double)xv * na.w;
      ln[4] += (double)xv * nb.x; ln[5] += (double)xv * nb.y;
      ln[6] += (double)xv * nb.z; ln[7] += (double)xv * nb.w;
    }
#pragma unroll
    for (int e = 0; e < 8; ++e) {
#pragma unroll
      for (int off = 1; off < 64; off <<= 1) {
        lg[e] += __shfl_xor(lg[e], off);
        ln[e] += __shfl_xor(ln[e], off);
      }
    }
    double nv[8];
#pragma unroll
    for (int e = 0; e < 8; ++e) {
      double nl = ln[e] + (double)bn[e];
      double sp = (nl > 30.0) ? nl : log1p(exp(nl));
      nv[e] = lg[e] + (double)bg[e] + (double)noise[(size_t)t * 8 + e] * sp;
    }
    int i0 = 0;
    double v0 = nv[0];
#pragma unroll
    for (int e = 1; e < 8; ++e)
      if (nv[e] > v0) { v0 = nv[e]; i0 = e; }
    int i1 = (i0 == 0) ? 1 : 0;
    double v1 = nv[i0 == 0 ? 1 : 0];
#pragma unroll
    for (int e = 0; e < 8; ++e)
      if (e != i0 && nv[e] > v1) { v1 = nv[e]; i1 = e; }
    if (l == 0) {
      double w1 = exp(v1 - v0);
      double s = 1.0 + w1;
      e0e1[t] = i0 | (i1 << 8);
      gg[t] = make_float2((float)(1.0 / s), (float)(w1 / s));
    }
  } else if (id < 12288) {
    // ---- zero d_out (replaces hipMemsetAsync) ----
    const int b = (id - 10240) * 1024 + tid;
    const float4 z = {0.f, 0.f, 0.f, 0.f};
#pragma unroll
    for (int j = 0; j < 4; ++j) out4[b + j * 256] = z;
  } else {
    // ---- Wd [E][H][D] -> WdT [E][D][H] bf16 (only launched in big-workspace layout) ----
    const int t = id - 12288;
    const int e = t >> 9, rem = t & 511;
    transpose_body(Wd, WdT, HDIM, DDIM, e, rem & 15, rem >> 4, tile);
  }
}

// ---------------- deterministic compaction: 8 blocks (1/expert), 8 waves each ----------------
__global__ __launch_bounds__(512) void compact_kernel(
    const int* __restrict__ e0e1, const float2* __restrict__ gg,
    int* __restrict__ tok_list, float* __restrict__ gate_list,
    int* __restrict__ counts, int* __restrict__ bases) {
  __shared__ int cmat[8][8];  // [wave][expert]
  const int e = blockIdx.x;
  const int wid = threadIdx.x >> 6, l = threadIdx.x & 63;
  const int t0w = wid * (T_TOK / 8);
  int c[8] = {0, 0, 0, 0, 0, 0, 0, 0};
  for (int i = 0; i < T_TOK / 8 / 64; ++i) {
    int p = e0e1[t0w + i * 64 + l];
    int ea = p & 255, eb = (p >> 8) & 255;
#pragma unroll
    for (int ee = 0; ee < 8; ++ee)
      c[ee] += __popcll(__ballot(ea == ee || eb == ee));
  }
  if (l == 0) {
#pragma unroll
    for (int ee = 0; ee < 8; ++ee) cmat[wid][ee] = c[ee];
  }
  __syncthreads();
  int base = 0;
  for (int ee = 0; ee < 8; ++ee) {
    if (ee < e) {
#pragma unroll
      for (int w = 0; w < 8; ++w) base += cmat[w][ee];
    }
  }
  int off = base;
#pragma unroll
  for (int w = 0; w < 8; ++w)
    if (w < wid) off += cmat[w][e];
  if (threadIdx.x == 0) {
    int tot = 0;
#pragma unroll
    for (int w = 0; w < 8; ++w) tot += cmat[w][e];
    counts[e] = tot;
    bases[e] = base;
  }
  for (int i = 0; i < T_TOK / 8 / 64; ++i) {
    int t = t0w + i * 64 + l;
    int p = e0e1[t];
    int ea = p & 255, eb = (p >> 8) & 255;
    int k = (ea == e) ? 0 : ((eb == e) ? 1 : -1);
    unsigned long long m = __ballot(k >= 0);
    if (k >= 0) {
      int pos = __popcll(m & ((1ull << l) - 1ull));
      float2 g = gg[t];
      tok_list[off + pos] = t;
      gate_list[off + pos] = (k == 0) ? g.x : g.y;
    }
    off += __popcll(m);
  }
}

// =====================================================================================
// m97-structure GEMM: 128x128 tile, BK=64, 4 waves (2x2, 64x64), single 32KB buffer,
// 2 barriers per K-step, chunk^=(row&7) swizzle both sides.
// Occupancy tuning (measured r12-r14): up best at (256,4) [LDS-capped at 4 blocks/CU];
// down best at (256,3) [4th block raised FETCH 285->304MB and slowed 131->140us].
// (256,5) spills acc (VGPR cap 48 < 68) -> never use.
// =====================================================================================

// ---------------- up GEMM: h = gelu(x_gathered @ Wu + bu) -> bf16 h_ws ----------------
__global__ __launch_bounds__(256, 4) void up_gemm_kernel(
    const unsigned short* __restrict__ xb, const unsigned short* __restrict__ WuT,
    const float* __restrict__ bu, const int* __restrict__ tok_list,
    const int* __restrict__ counts, const int* __restrict__ bases,
    unsigned short* __restrict__ h_ws) {
  const int e = blockIdx.z;
  const int count = counts[e];
  const int tileM = blockIdx.y;
  const int tileN = blockIdx.x;
  if (tileM * 128 >= count) return;
  const int base = bases[e];

  __shared__ char lds[36864];  // [0,16K) A 128x64 bf16 | [16K,32K) B | epilogue reuses 36K

  const int tid = threadIdx.x;
  const int wid = tid >> 6, l = tid & 63;
  const int wr = wid >> 1, wc = wid & 1;
  const int lr = l >> 3, j8 = l & 7;
  const int kc = (j8 ^ lr) << 4;  // pre-swizzled global k-chunk byte (row&7 == lr)
  const int cm1 = count - 1;

  const char* gA[4];
  const char* gB[4];
#pragma unroll
  for (int i = 0; i < 4; ++i) {
    int row = wid * 8 + lr + i * 32;  // 0..127
    int tok = tok_list[base + min(tileM * 128 + row, cm1)];
    gA[i] = (const char*)xb + (size_t)tok * 2048 + kc;
    gB[i] = (const char*)WuT + ((size_t)e * HDIM * DDIM + (size_t)(tileN * 128 + row) * DDIM) * 2 + kc;
  }

  const int fr = l & 15, kg = l >> 4;
  int aoff[4][2], boff[4][2];
#pragma unroll
  for (int m = 0; m < 4; ++m)
#pragma unroll
    for (int kk = 0; kk < 2; ++kk)
      aoff[m][kk] = (wr * 64 + m * 16 + fr) * 128 + ((((kk << 2) | kg) ^ (fr & 7)) << 4);
#pragma unroll
  for (int n = 0; n < 4; ++n)
#pragma unroll
    for (int kk = 0; kk < 2; ++kk)
      boff[n][kk] = 16384 + (wc * 64 + n * 16 + fr) * 128 + ((((kk << 2) | kg) ^ (fr & 7)) << 4);

  f32x4 acc[4][4];
  const f32x4 zz = {0.f, 0.f, 0.f, 0.f};
#pragma unroll
  for (int m = 0; m < 4; ++m)
#pragma unroll
    for (int n = 0; n < 4; ++n) acc[m][n] = zz;

  for (int kt = 0; kt < 16; ++kt) {
    __builtin_amdgcn_s_barrier();  // all waves done reading previous tile
    asm volatile("" ::: "memory");
#pragma unroll
    for (int i = 0; i < 4; ++i)
      __builtin_amdgcn_global_load_lds((as1_cchar*)(gA[i] + kt * 128),
                                       (as3_char*)lds + wid * 1024 + i * 4096, 16, 0, 0);
#pragma unroll
    for (int i = 0; i < 4; ++i)
      __builtin_amdgcn_global_load_lds((as1_cchar*)(gB[i] + kt * 128),
                                       (as3_char*)lds + 16384 + wid * 1024 + i * 4096, 16, 0, 0);
    asm volatile("s_waitcnt vmcnt(0)" ::: "memory");
    __builtin_amdgcn_s_barrier();
    asm volatile("" ::: "memory");

    short8 bf[4][2];
#pragma unroll
    for (int n = 0; n < 4; ++n) {
      bf[n][0] = *(const short8*)(lds + boff[n][0]);
      bf[n][1] = *(const short8*)(lds + boff[n][1]);
    }
    __builtin_amdgcn_s_setprio(1);
#pragma unroll
    for (int m = 0; m < 4; ++m) {
      short8 a0 = *(const short8*)(lds + aoff[m][0]);
      short8 a1 = *(const short8*)(lds + aoff[m][1]);
#pragma unroll
      for (int n = 0; n < 4; ++n) {
        acc[m][n] = __builtin_amdgcn_mfma_f32_16x16x32_bf16(a0, bf[n][0], acc[m][n], 0, 0, 0);
        acc[m][n] = __builtin_amdgcn_mfma_f32_16x16x32_bf16(a1, bf[n][1], acc[m][n], 0, 0, 0);
      }
    }
    __builtin_amdgcn_s_setprio(0);
  }

  // ---- epilogue: gelu -> bf16 -> LDS (stride 144) -> coalesced 16B row stores ----
  __builtin_amdgcn_s_barrier();  // everyone done with GEMM LDS
  asm volatile("" ::: "memory");
  char* epi = lds + wid * 9216;  // 64 rows x 144B per wave
#pragma unroll
  for (int n = 0; n < 4; ++n) {
    const float bv = bu[e * HDIM + tileN * 128 + wc * 64 + n * 16 + fr];
#pragma unroll
    for (int m = 0; m < 4; ++m) {
#pragma unroll
      for (int r = 0; r < 4; ++r) {
        float v = gelu_exact(acc[m][n][r] + bv);
        *(unsigned short*)(epi + (m * 16 + kg * 4 + r) * 144 + (n * 16 + fr) * 2) =
            (unsigned short)f2bf(v);
      }
    }
  }
#pragma unroll
  for (int jj = 0; jj < 8; ++jj) {
    const int row = jj * 8 + lr;
    const int grow = tileM * 128 + wr * 64 + row;
    if (grow < count) {
      uint4 v = *(const uint4*)(epi + row * 144 + j8 * 16);
      *(uint4*)((char*)h_ws +
                ((size_t)(base + grow) * HDIM + tileN * 128 + wc * 64 + j8 * 8) * 2) = v;
    }
  }
}

// ---------------- down GEMM: out += gate * (h @ Wd + bd), atomic scatter ----------------
__global__ __launch_bounds__(256, 3) void down_gemm_kernel(
    const unsigned short* __restrict__ h_ws, const unsigned short* __restrict__ WdT,
    const float* __restrict__ bd, const int* __restrict__ tok_list,
    const float* __restrict__ gate_list, const int* __restrict__ counts,
    const int* __restrict__ bases, float* __restrict__ out) {
  const int e = blockIdx.z;
  const int count = counts[e];
  const int tileM = blockIdx.y;
  const int tileN = blockIdx.x;
  if (tileM * 128 >= count) return;
  const int base = bases[e];

  __shared__ char lds[32768];

  const int tid = threadIdx.x;
  const int wid = tid >> 6, l = tid & 63;
  const int wr = wid >> 1, wc = wid & 1;
  const int lr = l >> 3, j8 = l & 7;
  const int kc = (j8 ^ lr) << 4;
  const int cm1 = count - 1;

  const char* gA[4];
  const char* gB[4];
#pragma unroll
  for (int i = 0; i < 4; ++i) {
    int row = wid * 8 + lr + i * 32;
    gA[i] = (const char*)h_ws + (size_t)(base + min(tileM * 128 + row, cm1)) * 4096 + kc;
    gB[i] = (const char*)WdT + ((size_t)e * DDIM * HDIM + (size_t)(tileN * 128 + row) * HDIM) * 2 + kc;
  }

  const int fr = l & 15, kg = l >> 4;
  int aoff[4][2], boff[4][2];
#pragma unroll
  for (int m = 0; m < 4; ++m)
#pragma unroll
    for (int kk = 0; kk < 2; ++kk)
      aoff[m][kk] = (wr * 64 + m * 16 + fr) * 128 + ((((kk << 2) | kg) ^ (fr & 7)) << 4);
#pragma unroll
  for (int n = 0; n < 4; ++n)
#pragma unroll
    for (int kk = 0; kk < 2; ++kk)
      boff[n][kk] = 16384 + (wc * 64 + n * 16 + fr) * 128 + ((((kk << 2) | kg) ^ (fr & 7)) << 4);

  f32x4 acc[4][4];
  const f32x4 zz = {0.f, 0.f, 0.f, 0.f};
#pragma unroll
  for (int m = 0; m < 4; ++m)
#pragma unroll
    for (int n = 0; n < 4; ++n) acc[m][n] = zz;

  for (int kt = 0; kt < 32; ++kt) {
    __builtin_amdgcn_s_barrier();
    asm volatile("" ::: "memory");
#pragma unroll
    for (int i = 0; i < 4; ++i)
      __builtin_amdgcn_global_load_lds((as1_cchar*)(gA[i] + kt * 128),
                                       (as3_char*)lds + wid * 1024 + i * 4096, 16, 0, 0);
#pragma unroll
    for (int i = 0; i < 4; ++i)
      __builtin_amdgcn_global_load_lds((as1_cchar*)(gB[i] + kt * 128),
                                       (as3_char*)lds + 16384 + wid * 1024 + i * 4096, 16, 0, 0);
    asm volatile("s_waitcnt vmcnt(0)" ::: "memory");
    __builtin_amdgcn_s_barrier();
    asm volatile("" ::: "memory");

    short8 bf[4][2];
#pragma unroll
    for (int n = 0; n < 4; ++n) {
      bf[n][0] = *(const short8*)(lds + boff[n][0]);
      bf[n][1] = *(const short8*)(lds + boff[n][1]);
    }
    __builtin_amdgcn_s_setprio(1);
#pragma unroll
    for (int m = 0; m < 4; ++m) {
      short8 a0 = *(const short8*)(lds + aoff[m][0]);
      short8 a1 = *(const short8*)(lds + aoff[m][1]);
#pragma unroll
      for (int n = 0; n < 4; ++n) {
        acc[m][n] = __builtin_amdgcn_mfma_f32_16x16x32_bf16(a0, bf[n][0], acc[m][n], 0, 0, 0);
        acc[m][n] = __builtin_amdgcn_mfma_f32_16x16x32_bf16(a1, bf[n][1], acc[m][n], 0, 0, 0);
      }
    }
    __builtin_amdgcn_s_setprio(0);
  }

  const int colBase = tileN * 128;
  float bdv[4];
#pragma unroll
  for (int n = 0; n < 4; ++n) bdv[n] = bd[e * DDIM + colBase + wc * 64 + n * 16 + fr];
#pragma unroll
  for (int m = 0; m < 4; ++m) {
#pragma unroll
    for (int r = 0; r < 4; ++r) {
      const int sl = tileM * 128 + wr * 64 + m * 16 + kg * 4 + r;
      if (sl < count) {
        const int idx = base + sl;
        const float gate = gate_list[idx];
        const int tok = tok_list[idx];
        float* orow = out + (size_t)tok * DDIM + colBase;
#pragma unroll
        for (int n = 0; n < 4; ++n) {
          const int col = wc * 64 + n * 16 + fr;
          atomicAdd(orow + col, (acc[m][n][r] + bdv[n]) * gate);
        }
      }
    }
  }
}

// ---------------- host launcher ----------------
// Layout A (ws_size >= 151,781,376 B): WdT gets its own region; Wd transpose fused in prep.
//   xb [0,16M) | WuT [16M,48M) | hws [48M,117.96M) | WdT [117.96M,151.5M) | small
// Layout B (fallback): WdT reuses [0,32M) after up_gemm; separate transpose.
extern "C" void kernel_launch(void* const* d_in, const int* in_sizes, int n_in,
                              void* d_out, int out_size, void* d_ws, size_t ws_size,
                              hipStream_t stream) {
  const float* x     = (const float*)d_in[0];
  const float* noise = (const float*)d_in[1];
  const float* Wg    = (const float*)d_in[2];
  const float* bg    = (const float*)d_in[3];
  const float* Wn    = (const float*)d_in[4];
  const float* bn    = (const float*)d_in[5];
  const float* Wu    = (const float*)d_in[6];
  const float* bu    = (const float*)d_in[7];
  const float* Wd    = (const float*)d_in[8];
  const float* bd    = (const float*)d_in[9];
  float* out = (float*)d_out;
  char* ws = (char*)d_ws;

  const bool bigws = (ws_size >= 151781376ull);

  unsigned short* xb  = (unsigned short*)(ws);                    // 16,777,216 B
  unsigned short* WuT = (unsigned short*)(ws + 16777216);         // 33,554,432 B
  unsigned short* hws = (unsigned short*)(ws + 50331648);         // 67,633,152 B
  unsigned short* WdT = bigws ? (unsigned short*)(ws + 117964800)  // own 32MB region
                              : (unsigned short*)(ws);             // reuse (after up_gemm)
  char* small = bigws ? (ws + 151519232) : (ws + 117964800);
  int*    e0e1      = (int*)(small);                              // 32,768 B
  float2* gg        = (float2*)(small + 32768);                   // 65,536 B
  int*    tok_list  = (int*)(small + 98304);                      // 65,536 B
  float*  gate_list = (float*)(small + 163840);                   // 65,536 B
  int*    counts    = (int*)(small + 229376);
  int*    bases     = (int*)(small + 229408);

  // prep: 4096 cast_x + 4096 trWu + 2048 router + 2048 zero-out [+ 4096 trWd if bigws]
  const int prep_blocks = bigws ? 16384 : 12288;
  prep_kernel<<<prep_blocks, 256, 0, stream>>>(x, noise, Wg, bg, Wn, bn, Wu, Wd,
                                               xb, WuT, WdT, e0e1, gg, (float4*)out);
  compact_kernel<<<NE, 512, 0, stream>>>(e0e1, gg, tok_list, gate_list, counts, bases);
  up_gemm_kernel<<<dim3(16, 64, NE), 256, 0, stream>>>(xb, WuT, bu, tok_list, counts, bases, hws);
  if (!bigws)
    transpose_cast64<<<dim3(DDIM / 64, HDIM / 64, NE), 256, 0, stream>>>(Wd, WdT, HDIM, DDIM);
  down_gemm_kernel<<<dim3(8, 64, NE), 256, 0, stream>>>(hws, WdT, bd, tok_list, gate_list, counts, bases, out);
}